// Round 4
// baseline (84.277 us; speedup 1.0000x reference)
//
#include <hip/hip_runtime.h>
#include <math.h>

#define BATCH   4
#define NPTS    8192
#define THREADS 256
#define NQTOT   (2 * BATCH * NPTS)      // 65536 (dir,b,query) triples
#define TPW     2048                    // targets per wave (4 waves cover 8192)
#define QPB     128                     // queries per block (4 A-frags per wave)

typedef _Float16 h8  __attribute__((ext_vector_type(8)));    // 4 VGPRs
typedef float    f16v __attribute__((ext_vector_type(16)));  // 16 VGPRs

// ---------------------------------------------------------------------------
// K0: transform both point clouds into MFMA-ready split-f16 B-records,
// INTERLEAVED so one wave's 64-lane fragment read is a single contiguous 1 KB
// block (lane n, half hi reads record 2*(t*32+n)+hi).
// Point t -> th (f16) + tl (f16 residual), t~ = th+tl accurate to ~2.5e-7.
// lo record (K slots 0..7):  [-2thx,-2thy,-2thz, tth, -2thx,-2thy,-2thz, ttl]
// hi record (K slots 8..15): [-2tlx,-2tly,-2tlz, 0,0,0,0,0]
// Paired with A = [qhx,qhy,qhz,1, qlx,qly,qlz,1 | qhx,qhy,qhz,0,...] one
// mfma_f32_32x32x16_f16 computes  tt - 2 q~.t~  (ql.tl term omitted,
// ~2e-5 absolute on sq).
// ---------------------------------------------------------------------------
__global__ __launch_bounds__(THREADS)
void chamfer_transform(const float* __restrict__ pred,
                       const float* __restrict__ target,
                       h8* __restrict__ trans_il)   // 65536 x 2 records
{
    const int p   = blockIdx.x * THREADS + threadIdx.x;   // 0..65535
    const int arr = p >> 15;                               // 0=pred, 1=target
    const int pb  = p & 32767;                             // (b*8192 + q)

    const float* src = (arr ? target : pred) + (size_t)pb * 3;
    const float x = src[0], y = src[1], z = src[2];

    const _Float16 hx = (_Float16)x;  const float lxf = x - (float)hx;
    const _Float16 hy = (_Float16)y;  const float lyf = y - (float)hy;
    const _Float16 hz = (_Float16)z;  const float lzf = z - (float)hz;
    const _Float16 lx = (_Float16)lxf, ly = (_Float16)lyf, lz = (_Float16)lzf;

    const float tx = (float)hx + (float)lx;
    const float ty = (float)hy + (float)ly;
    const float tz = (float)hz + (float)lz;
    const float tt = fmaf(tx, tx, fmaf(ty, ty, tz * tz));
    const _Float16 tth = (_Float16)tt;
    const _Float16 ttl = (_Float16)(tt - (float)tth);

    const _Float16 n2 = (_Float16)(-2.0f);
    h8 lo = { n2 * hx, n2 * hy, n2 * hz, tth,
              n2 * hx, n2 * hy, n2 * hz, ttl };
    h8 hi = { n2 * lx, n2 * ly, n2 * lz, (_Float16)0.0f,
              (_Float16)0.0f, (_Float16)0.0f, (_Float16)0.0f, (_Float16)0.0f };

    trans_il[2 * p]     = lo;
    trans_il[2 * p + 1] = hi;
}

// ---------------------------------------------------------------------------
// A-fragment builder: m = lane&31, k = 8*(lane>>5)+j  (32x32x16 f16 layout).
// ---------------------------------------------------------------------------
__device__ __forceinline__ h8 make_afrag(const float* __restrict__ qp, const int hi)
{
    const float x = qp[0], y = qp[1], z = qp[2];
    const _Float16 hx = (_Float16)x; const _Float16 lx = (_Float16)(x - (float)hx);
    const _Float16 hy = (_Float16)y; const _Float16 ly = (_Float16)(y - (float)hy);
    const _Float16 hz = (_Float16)z; const _Float16 lz = (_Float16)(z - (float)hz);
    const _Float16 one  = (_Float16)1.0f;
    const _Float16 zero = (_Float16)0.0f;
    if (hi == 0) return (h8){hx, hy, hz, one, lx, ly, lz, one};
    return (h8){hx, hy, hz, zero, zero, zero, zero, zero};
}

// ---------------------------------------------------------------------------
// K1 (fused, 4 A-frags/wave): block = 128 queries; each of its 4 waves runs
// those SAME 128 queries against a 2048-target quarter (all from L2, no
// staging, no hot-loop barriers).  4 A-fragments per wave double arithmetic
// intensity vs R3: each 2 KB tile-pair read feeds 8 MFMAs (was 4), halving
// total L2 B-traffic to 134 MB; the a+1 MFMAs issue while a's min3 folds
// run (MFMA pipe || VALU pipe inside one wave).  After the per-wave column
// butterfly, a 2 KB LDS merge completes the min across waves; all 4 waves
// share the fused |q|^2 + sqrt + sum epilogue; one float per block.
// Grid 512 = exactly 2 blocks/CU at (256,2); ~145 VGPR < 256 cap.
// C/D: col = lane&31, row = (reg&3) + 8*(reg>>2) + 4*(lane>>5)  [m74/m101].
// ---------------------------------------------------------------------------
__global__ __launch_bounds__(THREADS, 2)
void chamfer_min_kernel(const float* __restrict__ pred,
                        const float* __restrict__ target,
                        const h8* __restrict__ trans_il,
                        float* __restrict__ bsum)
{
    __shared__ float lmn[4][4][2][16];   // [set][wave][hi][reg] = 2 KB
    __shared__ float wsum[4];

    const int tid  = threadIdx.x;
    const int lane = tid & 63;
    const int wave = tid >> 6;
    const int n    = lane & 31;
    const int hi   = lane >> 5;

    const int bid = blockIdx.x;           // dir*256 + b*64 + qt
    const int qt  = bid & 63;
    const int b   = (bid >> 6) & 3;
    const int dir = bid >> 8;             // 0: q=pred, targets=target

    const int  qtbase = qt * QPB;
    const int  darr   = dir ^ 1;          // target-array index in trans
    const float* qraw = ((dir == 0) ? pred : target) + (size_t)b * NPTS * 3;

    // ---- four A fragments: queries qtbase + {0,32,64,96} + n ----
    const h8 a0 = make_afrag(qraw + (size_t)(qtbase +      n) * 3, hi);
    const h8 a1 = make_afrag(qraw + (size_t)(qtbase + 32 + n) * 3, hi);
    const h8 a2 = make_afrag(qraw + (size_t)(qtbase + 64 + n) * 3, hi);
    const h8 a3 = make_afrag(qraw + (size_t)(qtbase + 96 + n) * 3, hi);

    float mn0[16], mn1[16], mn2[16], mn3[16];
    #pragma unroll
    for (int i = 0; i < 16; ++i) {
        mn0[i] = 3.0e38f; mn1[i] = 3.0e38f; mn2[i] = 3.0e38f; mn3[i] = 3.0e38f;
    }

    // wave w covers targets [w*TPW, (w+1)*TPW)
    const size_t gbase = (size_t)(darr * 4 + b) * NPTS + (size_t)wave * TPW;
    const h8* bp = trans_il + 2 * (gbase + n) + hi;
    const f16v zc = {};

    #pragma unroll 2
    for (int tp = 0; tp < TPW / 64; ++tp) {
        const h8 b0 = bp[tp * 128];           // tile 2*tp
        const h8 b1 = bp[tp * 128 + 64];      // tile 2*tp+1

        {
            const f16v dA = __builtin_amdgcn_mfma_f32_32x32x16_f16(a0, b0, zc, 0, 0, 0);
            const f16v dB = __builtin_amdgcn_mfma_f32_32x32x16_f16(a0, b1, zc, 0, 0, 0);
            #pragma unroll
            for (int i = 0; i < 16; ++i)
                mn0[i] = fminf(fminf(dA[i], dB[i]), mn0[i]);   // -> v_min3_f32
        }
        {
            const f16v dA = __builtin_amdgcn_mfma_f32_32x32x16_f16(a1, b0, zc, 0, 0, 0);
            const f16v dB = __builtin_amdgcn_mfma_f32_32x32x16_f16(a1, b1, zc, 0, 0, 0);
            #pragma unroll
            for (int i = 0; i < 16; ++i)
                mn1[i] = fminf(fminf(dA[i], dB[i]), mn1[i]);
        }
        {
            const f16v dA = __builtin_amdgcn_mfma_f32_32x32x16_f16(a2, b0, zc, 0, 0, 0);
            const f16v dB = __builtin_amdgcn_mfma_f32_32x32x16_f16(a2, b1, zc, 0, 0, 0);
            #pragma unroll
            for (int i = 0; i < 16; ++i)
                mn2[i] = fminf(fminf(dA[i], dB[i]), mn2[i]);
        }
        {
            const f16v dA = __builtin_amdgcn_mfma_f32_32x32x16_f16(a3, b0, zc, 0, 0, 0);
            const f16v dB = __builtin_amdgcn_mfma_f32_32x32x16_f16(a3, b1, zc, 0, 0, 0);
            #pragma unroll
            for (int i = 0; i < 16; ++i)
                mn3[i] = fminf(fminf(dA[i], dB[i]), mn3[i]);
        }
    }

    // ---- butterfly min over the 32 columns (targets) within the wave ----
    #pragma unroll
    for (int mask = 1; mask <= 16; mask <<= 1) {
        #pragma unroll
        for (int i = 0; i < 16; ++i) {
            mn0[i] = fminf(mn0[i], __shfl_xor(mn0[i], mask, 64));
            mn1[i] = fminf(mn1[i], __shfl_xor(mn1[i], mask, 64));
            mn2[i] = fminf(mn2[i], __shfl_xor(mn2[i], mask, 64));
            mn3[i] = fminf(mn3[i], __shfl_xor(mn3[i], mask, 64));
        }
    }

    // ---- cross-wave merge via LDS ----
    if (n == 0) {
        #pragma unroll
        for (int i = 0; i < 16; ++i) {
            lmn[0][wave][hi][i] = mn0[i];
            lmn[1][wave][hi][i] = mn1[i];
            lmn[2][wave][hi][i] = mn2[i];
            lmn[3][wave][hi][i] = mn3[i];
        }
    }
    __syncthreads();

    // ---- wave a finalizes query set a: min over waves, |q|^2, sqrt, sum ----
    const int a = wave;
    float acc = 0.0f;
    if (lane < 32) {
        const int h2 = lane >> 4;           // hi half
        const int i  = lane & 15;           // reg index
        const float m = fminf(fminf(lmn[a][0][h2][i], lmn[a][1][h2][i]),
                              fminf(lmn[a][2][h2][i], lmn[a][3][h2][i]));
        const int r = (i & 3) + 8 * (i >> 2) + 4 * h2;       // row 0..31
        const int q = qtbase + 32 * a + r;
        const float* qp = qraw + (size_t)q * 3;              // L1-hot
        const float qq = fmaf(qp[0], qp[0], fmaf(qp[1], qp[1], qp[2] * qp[2]));
        acc = sqrtf(fmaxf(qq + m, 1e-12f));
    }
    #pragma unroll
    for (int off = 32; off > 0; off >>= 1)
        acc += __shfl_down(acc, off, 64);
    if (lane == 0) wsum[wave] = acc;
    __syncthreads();
    if (tid == 0) bsum[bid] = wsum[0] + wsum[1] + wsum[2] + wsum[3];
}

// ---------------------------------------------------------------------------
// K3: sum 512 block sums, write mean over batches.
// ---------------------------------------------------------------------------
__global__ __launch_bounds__(THREADS)
void chamfer_reduce2(const float* __restrict__ bsum,
                     float* __restrict__ out)
{
    const int tid = threadIdx.x;
    float v = bsum[tid] + bsum[256 + tid];
    #pragma unroll
    for (int off = 32; off > 0; off >>= 1)
        v += __shfl_down(v, off, 64);

    __shared__ float wsum[4];
    if ((tid & 63) == 0) wsum[tid >> 6] = v;
    __syncthreads();
    if (tid == 0) out[0] = (wsum[0] + wsum[1] + wsum[2] + wsum[3]) * (1.0f / BATCH);
}

extern "C" void kernel_launch(void* const* d_in, const int* in_sizes, int n_in,
                              void* d_out, int out_size, void* d_ws, size_t ws_size,
                              hipStream_t stream)
{
    const float* pred   = (const float*)d_in[0];
    const float* target = (const float*)d_in[1];
    float* out          = (float*)d_out;

    // ws layout: trans_il 2 MB | bsum 2 KB
    h8*    trans_il = (h8*)d_ws;                               // 131072 recs
    float* bsum     = (float*)((char*)d_ws + (size_t)131072 * 16);

    chamfer_transform<<<NQTOT / THREADS, THREADS, 0, stream>>>(
        pred, target, trans_il);   // 256 blocks

    chamfer_min_kernel<<<2 * BATCH * 64, THREADS, 0, stream>>>(
        pred, target, trans_il, bsum);   // 512 blocks

    chamfer_reduce2<<<1, THREADS, 0, stream>>>(bsum, out);
}